// Round 7
// baseline (800.396 us; speedup 1.0000x reference)
//
#include <hip/hip_runtime.h>
#include <stdint.h>
#include <stddef.h>

// ---------------- problem constants ----------------
#define B_    2
#define S_    4096
#define E_    2560
#define H_    8
#define HKV_  4
#define D_    256
#define F_    4096      // (H+2*HKV)*D
#define HD_   2048      // H*D
#define WIN_  1024

typedef __bf16 bf16;
typedef bf16  bf16x8 __attribute__((ext_vector_type(8)));
typedef bf16  bf16x4 __attribute__((ext_vector_type(4)));
typedef float f32x4  __attribute__((ext_vector_type(4)));
typedef uint32_t u32;

// async global->LDS, 16B per lane. HW dest = wave-uniform(first-lane) base + lane*16.
__device__ __forceinline__ void gl_lds16(const void* g, void* l) {
  __builtin_amdgcn_global_load_lds((const __attribute__((address_space(1))) void*)g,
                                   (__attribute__((address_space(3))) void*)l, 16, 0, 0);
}

__device__ __forceinline__ void bar_mf() {
  asm volatile("" ::: "memory");
  __builtin_amdgcn_s_barrier();
  asm volatile("" ::: "memory");
}

__device__ __forceinline__ u32 pkbf16(float a, float b) {
  union { bf16 h[2]; u32 u; } cv;
  cv.h[0] = (bf16)a; cv.h[1] = (bf16)b; return cv.u;
}

// ---------------- plain f32 -> bf16 convert ----------------
__global__ __launch_bounds__(256) void to_bf16_plain(const float* __restrict__ src,
                                                     bf16* __restrict__ dst, int n) {
  const int i = (blockIdx.x * 256 + threadIdx.x) * 8;
  if (i >= n) return;
  f32x4 a = *(const f32x4*)(src + i);
  f32x4 b = *(const f32x4*)(src + i + 4);
  bf16x8 o;
#pragma unroll
  for (int j = 0; j < 4; ++j) { o[j] = (bf16)a[j]; o[j + 4] = (bf16)b[j]; }
  *(bf16x8*)(dst + i) = o;
}

// ============ 256xBN NT GEMM (bf16), BK=64, 8 waves (2M x 4N), 2-barrier pipeline ====
// EPI==1: gemm1 epilogue (scatter q/k natural + v transposed).  EPI==0: f32 C out.
// See round-6 notes: linear LDS dest + inverse-XOR src staging; per K-tile only two
// barriers (M: B(t) reads done -> stage B(t+2); T: tile boundary, vmcnt(2*NBH)).
template <int EPI, int BN>
__global__ __launch_bounds__(512, 2) void gemm_8ph(
    const bf16* __restrict__ A, const bf16* __restrict__ Bw, int Kd, int NT,
    bf16* __restrict__ qo, bf16* __restrict__ ko, bf16* __restrict__ vto,
    float* __restrict__ C, int Nout, int row_base) {
  constexpr int NBH = BN / 128;        // B half-buffers
  constexpr int JT  = BN / 64;         // j-tiles per wave
  __shared__ bf16 Lds[2][2 + NBH][128 * 64];

  const int tid  = threadIdx.x;
  const int lane = tid & 63;
  const int wave = tid >> 6;
  const int wm   = wave >> 2;        // 0..1  (M half)
  const int wn   = wave & 3;         // 0..3  (N quarter)
  const int l16  = lane & 15;
  const int quad = lane >> 4;

  // bijective XCD swizzle (nwg % 8 == 0 for all our grids)
  const int nwg  = gridDim.x * gridDim.y;
  const int obid = blockIdx.y * gridDim.x + blockIdx.x;
  const int bid  = (obid & 7) * (nwg >> 3) + (obid >> 3);
  const int mt   = bid / gridDim.x;
  const int ntl  = bid - mt * gridDim.x;
  const int row0 = mt * 256, col0 = ntl * BN;

  const bf16* Ah[2] = {A + (size_t)row0 * Kd, A + (size_t)(row0 + 128) * Kd};
  const bf16* Bh[2] = {Bw + (size_t)col0 * Kd,
                       Bw + (size_t)(col0 + (NBH == 2 ? 128 : 0)) * Kd};

  auto stage = [&](int dbf, int hf, const bf16* src, int k0) {
#pragma unroll
    for (int i = 0; i < 2; ++i) {
      const int g = tid + i * 512;         // 0..1023
      const int r = g >> 3, c = g & 7;
      gl_lds16(src + (size_t)r * Kd + k0 + ((c ^ (r & 7)) << 3),
               &Lds[dbf][hf][0] + g * 8);
    }
  };
  auto rdA = [&](int dbf, int i, int ks) -> bf16x8 {
    const int r = i * 16 + l16;
    return *(const bf16x8*)&Lds[dbf][wm][r * 64 + (((ks * 4 + quad) ^ (r & 7)) << 3)];
  };
  auto rdB = [&](int dbf, int j, int ks) -> bf16x8 {
    const int colt = wn * (BN / 4) + j * 16 + l16;     // col within tile
    const int r = colt & 127;
    return *(const bf16x8*)&Lds[dbf][2 + (colt >> 7)][r * 64 + (((ks * 4 + quad) ^ (r & 7)) << 3)];
  };

  f32x4 acc[8][JT] = {};

  // prologue: tile0 all + tile1 B; wait so only tile1's B (2*NBH loads) in flight
  stage(0, 0, Ah[0], 0); stage(0, 1, Ah[1], 0);
#pragma unroll
  for (int h = 0; h < NBH; ++h) stage(0, 2 + h, Bh[h], 0);
  if (NT > 1) {
#pragma unroll
    for (int h = 0; h < NBH; ++h) stage(1, 2 + h, Bh[h], 64);
  }
  if constexpr (NBH == 2) asm volatile("s_waitcnt vmcnt(4)" ::: "memory");
  else                    asm volatile("s_waitcnt vmcnt(2)" ::: "memory");
  bar_mf();

  int db = 0;
  for (int t = 0; t < NT; ++t, db ^= 1) {
    const int k1 = (t + 1) * 64, k2 = (t + 2) * 64;
    const bool st1 = (t + 1 < NT), st2 = (t + 2 < NT);

    bf16x8 bfr[JT][2], a01[2][2], a23[2][2], a45[2][2], a67[2][2];
#pragma unroll
    for (int j = 0; j < JT; ++j) { bfr[j][0] = rdB(db, j, 0); bfr[j][1] = rdB(db, j, 1); }
#pragma unroll
    for (int i = 0; i < 2; ++i) { a01[i][0] = rdA(db, i, 0);     a01[i][1] = rdA(db, i, 1); }
#pragma unroll
    for (int i = 0; i < 2; ++i) { a23[i][0] = rdA(db, i + 2, 0); a23[i][1] = rdA(db, i + 2, 1); }
    if (st1) { stage(db ^ 1, 0, Ah[0], k1); stage(db ^ 1, 1, Ah[1], k1); }

    __builtin_amdgcn_s_setprio(1);
#pragma unroll
    for (int i = 0; i < 2; ++i)
#pragma unroll
      for (int j = 0; j < JT; ++j) {
        acc[i][j] = __builtin_amdgcn_mfma_f32_16x16x32_bf16(a01[i][0], bfr[j][0], acc[i][j], 0, 0, 0);
        acc[i][j] = __builtin_amdgcn_mfma_f32_16x16x32_bf16(a01[i][1], bfr[j][1], acc[i][j], 0, 0, 0);
      }
    __builtin_amdgcn_s_setprio(0);

#pragma unroll
    for (int i = 0; i < 2; ++i) { a45[i][0] = rdA(db, i + 4, 0); a45[i][1] = rdA(db, i + 4, 1); }

    __builtin_amdgcn_s_setprio(1);
#pragma unroll
    for (int i = 0; i < 2; ++i)
#pragma unroll
      for (int j = 0; j < JT; ++j) {
        acc[i + 2][j] = __builtin_amdgcn_mfma_f32_16x16x32_bf16(a23[i][0], bfr[j][0], acc[i + 2][j], 0, 0, 0);
        acc[i + 2][j] = __builtin_amdgcn_mfma_f32_16x16x32_bf16(a23[i][1], bfr[j][1], acc[i + 2][j], 0, 0, 0);
      }
    __builtin_amdgcn_s_setprio(0);

    bar_mf();                       // barrier M: every wave finished reading B(t)
    if (st2) {
      stage(db, 2, Bh[0], k2);
      if constexpr (NBH == 2) stage(db, 3, Bh[1], k2);
    }
#pragma unroll
    for (int i = 0; i < 2; ++i) { a67[i][0] = rdA(db, i + 6, 0); a67[i][1] = rdA(db, i + 6, 1); }

    __builtin_amdgcn_s_setprio(1);
#pragma unroll
    for (int i = 0; i < 2; ++i)
#pragma unroll
      for (int j = 0; j < JT; ++j) {
        acc[i + 4][j] = __builtin_amdgcn_mfma_f32_16x16x32_bf16(a45[i][0], bfr[j][0], acc[i + 4][j], 0, 0, 0);
        acc[i + 4][j] = __builtin_amdgcn_mfma_f32_16x16x32_bf16(a45[i][1], bfr[j][1], acc[i + 4][j], 0, 0, 0);
      }
    __builtin_amdgcn_s_setprio(0);

    __builtin_amdgcn_s_setprio(1);
#pragma unroll
    for (int i = 0; i < 2; ++i)
#pragma unroll
      for (int j = 0; j < JT; ++j) {
        acc[i + 6][j] = __builtin_amdgcn_mfma_f32_16x16x32_bf16(a67[i][0], bfr[j][0], acc[i + 6][j], 0, 0, 0);
        acc[i + 6][j] = __builtin_amdgcn_mfma_f32_16x16x32_bf16(a67[i][1], bfr[j][1], acc[i + 6][j], 0, 0, 0);
      }
    __builtin_amdgcn_s_setprio(0);

    if (st2) {
      if constexpr (NBH == 2) asm volatile("s_waitcnt vmcnt(4)" ::: "memory");
      else                    asm volatile("s_waitcnt vmcnt(2)" ::: "memory");
    } else {
      asm volatile("s_waitcnt vmcnt(0)" ::: "memory");
    }
    bar_mf();                       // barrier T: tile t+1 may read A(t+1)/B(t+1)
  }

  // ---- epilogue. C/D layout (m89): col = lane&15 (B), row = quad*4 + reg (A).
#pragma unroll
  for (int i = 0; i < 8; ++i) {
    const int rbase = row_base + row0 + wm * 128 + i * 16 + quad * 4;
#pragma unroll
    for (int j = 0; j < JT; ++j) {
      const int c = col0 + wn * (BN / 4) + j * 16 + l16;
      if constexpr (EPI == 1) {
        int head = c >> 8;                             // 0..15
        const int d = c & 255;
        if (head < 12) {
          bf16* base; int nh;
          if (head < 8) { base = qo; nh = H_; }
          else          { base = ko; nh = HKV_; head -= 8; }
#pragma unroll
          for (int rr = 0; rr < 4; ++rr) {
            const int row = rbase + rr;
            const int bb = row >> 12, s = row & 4095;
            base[(((size_t)(bb * nh + head) * S_) + s) * D_ + d] = (bf16)acc[i][j][rr];
          }
        } else {
          const int kh = head - 12;
          const int bb = rbase >> 12, s0 = rbase & 4095;
          bf16x4 pk;
#pragma unroll
          for (int rr = 0; rr < 4; ++rr) pk[rr] = (bf16)acc[i][j][rr];
          *(bf16x4*)(vto + (((size_t)(bb * HKV_ + kh) * D_ + d) * S_ + s0)) = pk;
        }
      } else {
#pragma unroll
        for (int rr = 0; rr < 4; ++rr)
          C[(size_t)(rbase + rr) * Nout + c] = acc[i][j][rr];   // f32 store
      }
    }
  }
}

// ---------------- RMSNorm + RoPE, in-place ----------------
__global__ __launch_bounds__(192) void normrope2(
    bf16* __restrict__ q, bf16* __restrict__ k,
    const float* __restrict__ fcos, const float* __restrict__ fsin,
    const int* __restrict__ widx,
    const float* __restrict__ qnw, const float* __restrict__ knw) {
  const int bx  = blockIdx.x;
  const int b   = bx >> 12;
  const int s   = bx & 4095;
  const int tid = threadIdx.x;
  const int hh  = tid >> 4;
  const int g   = tid & 15;
  const int d0  = g * 16;

  const bool isq = (hh < 8);
  bf16* rowp = isq ? (q + (((size_t)(b * H_ + hh) * S_ + s) * D_ + d0))
                   : (k + (((size_t)(b * HKV_ + (hh - 8)) * S_ + s) * D_ + d0));
  float x[16];
  {
    bf16x8 v0 = *(const bf16x8*)rowp;
    bf16x8 v1 = *(const bf16x8*)(rowp + 8);
#pragma unroll
    for (int i = 0; i < 8; ++i) { x[i] = (float)v0[i]; x[i + 8] = (float)v1[i]; }
  }

  float ssq = 0.f;
#pragma unroll
  for (int i = 0; i < 16; ++i) ssq += x[i] * x[i];
#pragma unroll
  for (int off = 1; off < 16; off <<= 1) ssq += __shfl_xor(ssq, off);
  const float sc = rsqrtf(ssq * (1.0f / 256.0f) + 1e-6f);
  const float* w = isq ? qnw : knw;
#pragma unroll
  for (int i = 0; i < 16; ++i) x[i] = x[i] * sc * (1.0f + w[d0 + i]);

  const int fbase = (g < 8) ? d0 : (d0 - 128);
  const float* cp = fcos + (size_t)s * 128 + fbase;
  const float* sp = fsin + (size_t)s * 128 + fbase;
#pragma unroll
  for (int i = 0; i < 16; ++i) {
    const float c = cp[i], sn = sp[i];
    const float other = __shfl_xor(x[i], 8);
    x[i] = (g < 8) ? (x[i] * c - other * sn)
                   : (x[i] * c + other * sn);
  }
  if (isq) {
#pragma unroll
    for (int i = 0; i < 16; ++i) x[i] *= 0.0625f;   // SCALING = 256^-0.5
  }

  bf16x8 o0, o1;
#pragma unroll
  for (int i = 0; i < 8; ++i) { o0[i] = (bf16)x[i]; o1[i] = (bf16)x[i + 8]; }

  bf16* dstp = isq ? rowp
                   : (k + (((size_t)(b * HKV_ + (hh - 8)) * S_ + widx[s]) * D_ + d0));
  *(bf16x8*)dstp = o0;
  *(bf16x8*)(dstp + 8) = o1;
}

// ---------------- MFMA flash attention: 2 q-groups/wave, shared K/V reads ----------
// 512 blocks x 4 waves; block = 128 q rows, wave = 32 (two 16-row fragment groups).
// Each K/V LDS fragment is read ONCE and feeds TWO MFMAs (group A + group B) --
// halves LDS-pipe traffic per score vs 16-row waves.
// Fixed-max softmax (softcap bounds scores to +-50):
//   p = exp(50*tanh(x/50) - 50) = exp2(-144.2695 / (exp2(0.0577078*x) + 1))
// K rows staged PERMUTED (slot s holds key 8*((s>>2)&3) + 4*(s>>4) + (s&3)) so the
// QK C-layout aligns with PV's B-operand: pf = lane-local pack, zero shuffles.
// V tile [256 d][32 keys] staged with chunk XOR ((row>>1)&3) -> conflict-free b128.
// XCD swizzle maps each XCD to exactly one (b,kh): K+Vt = 4MB fits its private L2.
__global__ __launch_bounds__(256, 2) void attn_mfma(const bf16* __restrict__ Q,
                                                    const bf16* __restrict__ K,
                                                    const bf16* __restrict__ Vt,
                                                    bf16* __restrict__ out) {
  __shared__ bf16 Ks[2][32 * 256];
  __shared__ bf16 Vs[2][256 * 32];

  const int hw  = blockIdx.x;
  const int lid = (hw & 7) * 64 + (hw >> 3);    // bijective (512 % 8 == 0)
  const int bx  = lid & 31;                     // q-block of 128 rows
  const int bh  = lid >> 5;                     // b*8 + h
  const int b   = bh >> 3, h = bh & 7, kh = h >> 1;

  const int lane = threadIdx.x & 63;
  const int wave = threadIdx.x >> 6;
  const int l16  = lane & 15;
  const int qd   = lane >> 4;
  const int swz  = l16 & 7;

  const int q0w = bx * 128 + wave * 32;         // wave's 32 q rows

  const bf16* Kb = K  + ((size_t)(b * HKV_ + kh) * S_) * D_;
  const bf16* Vb = Vt + ((size_t)(b * HKV_ + kh) * D_) * S_;

  // Q fragments for both groups (B-operand); SCALING pre-applied in normrope
  bf16x8 qf[2][8];
#pragma unroll
  for (int g = 0; g < 2; ++g) {
    const bf16* qp = Q + (((size_t)(b * H_ + h) * S_ + q0w + g * 16 + l16) * D_) + qd * 8;
#pragma unroll
    for (int kc = 0; kc < 8; ++kc) qf[g][kc] = *(const bf16x8*)(qp + kc * 32);
  }

  f32x4 Od[2][16] = {};                         // per group: d = dt*16+qd*4+r, q = l16
  float lsum[2] = {0.f, 0.f};

  int lo = bx * 128 - (WIN_ - 1); if (lo < 0) lo = 0;
  lo &= ~31;
  const int t1 = bx * 128 + 96;                 // last tile (covers q up to bx*128+127)

  auto stage = [&](int buf, int kt) {
#pragma unroll
    for (int i = 0; i < 4; ++i) {
      const int r0  = wave * 8 + i * 2;
      const int row = r0 + (lane >> 5);         // LDS slot 0..31
      const int c   = lane & 31;
      // permuted key for slot: perm(s) = 8*((s>>2)&3) + 4*(s>>4) + (s&3)
      const int pk = (((row >> 2) & 3) << 3) + ((row >> 4) << 2) + (row & 3);
      gl_lds16(Kb + (size_t)(kt + pk) * D_ + ((c ^ (row & 7)) * 8),
               &Ks[buf][r0 * 256] + lane * 8);
    }
#pragma unroll
    for (int i = 0; i < 4; ++i) {
      const int d0 = (wave * 4 + i) * 16;
      const int d  = d0 + (lane >> 2);
      // V bank swizzle: LDS[row][chunk] holds global chunk (chunk ^ ((row>>1)&3));
      // row = lane>>2 within 16-row group -> (row>>1)&3 = (lane>>3)&3
      const int cs = (lane & 3) ^ ((lane >> 3) & 3);
      gl_lds16(Vb + (size_t)d * S_ + kt + cs * 8,
               &Vs[buf][d0 * 32] + lane * 8);
    }
  };

  stage(0, lo);
  int buf = 0;

  const float c1 = 0.05770780163555853f;        // 2*log2(e)/50
  const float c2 = -144.26950408889634f;        // -100*log2(e)

  for (int kt = lo; kt <= t1; kt += 32) {
    const bool pre = (kt + 32 <= t1);
    if (pre) {
      stage(buf ^ 1, kt + 32);
      asm volatile("s_waitcnt vmcnt(8)" ::: "memory");
    } else {
      asm volatile("s_waitcnt vmcnt(0)" ::: "memory");
    }
    __builtin_amdgcn_s_barrier();
    asm volatile("" ::: "memory");

    // wave-dead only if dead for BOTH groups (rows q0w .. q0w+31)
    const bool dead = (kt > q0w + 31) || (kt + 31 < q0w - (WIN_ - 1));
    if (!dead) {
      // ---- S^T both groups, K fragments read ONCE
      f32x4 sacc[2][2] = {};
#pragma unroll
      for (int kc = 0; kc < 8; ++kc) {
        const int ch = ((kc * 4 + qd) ^ swz) * 8;
        bf16x8 k0 = *(const bf16x8*)&Ks[buf][l16 * 256 + ch];
        bf16x8 k1 = *(const bf16x8*)&Ks[buf][(l16 + 16) * 256 + ch];
        sacc[0][0] = __builtin_amdgcn_mfma_f32_16x16x32_bf16(k0, qf[0][kc], sacc[0][0], 0, 0, 0);
        sacc[0][1] = __builtin_amdgcn_mfma_f32_16x16x32_bf16(k1, qf[0][kc], sacc[0][1], 0, 0, 0);
        sacc[1][0] = __builtin_amdgcn_mfma_f32_16x16x32_bf16(k0, qf[1][kc], sacc[1][0], 0, 0, 0);
        sacc[1][1] = __builtin_amdgcn_mfma_f32_16x16x32_bf16(k1, qf[1][kc], sacc[1][1], 0, 0, 0);
      }

      // ---- softmax per group: p = exp(cap(x) - 50); mask only on edge tiles
      union { u32 u[4]; bf16x8 v; } pf[2];
      const int kb0 = kt + qd * 8;
#pragma unroll
      for (int g = 0; g < 2; ++g) {
        const int qg = q0w + g * 16;            // group's min row
        const int iq = qg + l16;
        const bool interior = (kt + 31 <= qg) && (kt >= qg - 1008);
        float p[8];
#pragma unroll
        for (int t = 0; t < 2; ++t)
#pragma unroll
          for (int r = 0; r < 4; ++r) {
            const float x = sacc[g][t][r];
            const float wv = __builtin_amdgcn_rcpf(exp2f(x * c1) + 1.0f);
            float pp = exp2f(c2 * wv);
            if (!interior) {
              const int key = kb0 + t * 4 + r;
              pp = (key <= iq && (iq - key) < WIN_) ? pp : 0.f;
            }
            p[t * 4 + r] = pp;
            lsum[g] += pp;
          }
        pf[g].u[0] = pkbf16(p[0], p[1]);
        pf[g].u[1] = pkbf16(p[2], p[3]);
        pf[g].u[2] = pkbf16(p[4], p[5]);
        pf[g].u[3] = pkbf16(p[6], p[7]);
      }

      // ---- O^T += Vt x P, V fragments read ONCE (swizzled, conflict-free)
#pragma unroll
      for (int dt = 0; dt < 16; ++dt) {
        const int ch = (qd ^ ((l16 >> 1) & 3)) * 8;
        bf16x8 vf = *(const bf16x8*)&Vs[buf][(dt * 16 + l16) * 32 + ch];
        Od[0][dt] = __builtin_amdgcn_mfma_f32_16x16x32_bf16(vf, pf[0].v, Od[0][dt], 0, 0, 0);
        Od[1][dt] = __builtin_amdgcn_mfma_f32_16x16x32_bf16(vf, pf[1].v, Od[1][dt], 0, 0, 0);
      }
    }

    asm volatile("" ::: "memory");
    __builtin_amdgcn_s_barrier();
    buf ^= 1;
  }

  // epilogue: reduce l across quads (same l16 -> same q-row), then normalize
#pragma unroll
  for (int g = 0; g < 2; ++g) {
    float l = lsum[g] + __shfl_xor(lsum[g], 16);
    l += __shfl_xor(l, 32);
    const float inv = 1.f / l;
    const int iq = q0w + g * 16 + l16;
    bf16* op = out + ((size_t)b * S_ + iq) * HD_ + h * D_ + qd * 4;
#pragma unroll
    for (int dt = 0; dt < 16; ++dt) {
      bf16x4 o4;
#pragma unroll
      for (int r = 0; r < 4; ++r) o4[r] = (bf16)(Od[g][dt][r] * inv);
      *(bf16x4*)(op + dt * 16) = o4;
    }
  }
}

// ---------------- launch ----------------
// Small path (96 MiB): wb_bf [0,20), hb chunk [20,30), q [32,64), k [64,80), vt [80,96)
//   after gemm1: att_o [0,32); after attn: wo_bf [32,42) (q dead)
// Big path (ws >= 126 MiB): hb full [20,60), q [60,92), k [92,108), vt [108,124).
extern "C" void kernel_launch(void* const* d_in, const int* in_sizes, int n_in,
                              void* d_out, int out_size, void* d_ws, size_t ws_size,
                              hipStream_t stream) {
  const float* hidden = (const float*)d_in[0];
  const float* fcos   = (const float*)d_in[1];
  const float* fsin   = (const float*)d_in[2];
  const int*   widx   = (const int*)d_in[3];
  const float* wqkv   = (const float*)d_in[8];
  const float* wo     = (const float*)d_in[9];
  const float* qnw    = (const float*)d_in[10];
  const float* knw    = (const float*)d_in[11];
  float* out = (float*)d_out;    // reference output dtype = float32

  char* ws = (char*)d_ws;
  const size_t MB = 1024 * 1024;
  const bool big = ws_size >= 126 * MB;

  bf16* wb_bf = (bf16*)(ws);                     // [0,20M)
  bf16* hb_bf = (bf16*)(ws + 20 * MB);           // chunk (10M) or full (40M)
  bf16* q_ws  = (bf16*)(ws + (big ? 60 : 32) * MB);
  bf16* k_ws  = (bf16*)(ws + (big ? 92 : 64) * MB);
  bf16* vt_ws = (bf16*)(ws + (big ? 108 : 80) * MB);
  bf16* att_o = (bf16*)(ws);                     // [0,32M), after gemm1
  bf16* wo_bf = (bf16*)(ws + 32 * MB);           // [32,42M), after attn

  // w_qkv f32 -> bf16 (once)
  to_bf16_plain<<<(F_ * E_ / 8 + 255) / 256, 256, 0, stream>>>(wqkv, wb_bf, F_ * E_);

  // hidden -> bf16 (chunks on small ws), then pipelined bf16 NT GEMM per chunk
  const int nch   = big ? 1 : 4;
  const int chrow = (B_ * S_) / nch;             // 8192 or 2048 rows
  for (int c = 0; c < nch; ++c) {
    const int row_base = c * chrow;
    to_bf16_plain<<<(chrow * E_ / 8 + 255) / 256, 256, 0, stream>>>(
        hidden + (size_t)row_base * E_, hb_bf, chrow * E_);
    if (big)
      gemm_8ph<1, 256><<<dim3(F_ / 256, chrow / 256), 512, 0, stream>>>(
          hb_bf, wb_bf, E_, E_ / 64, q_ws, k_ws, vt_ws, nullptr, 0, row_base);
    else
      gemm_8ph<1, 128><<<dim3(F_ / 128, chrow / 256), 512, 0, stream>>>(
          hb_bf, wb_bf, E_, E_ / 64, q_ws, k_ws, vt_ws, nullptr, 0, row_base);
  }

  normrope2<<<dim3(B_ * S_), 192, 0, stream>>>(q_ws, k_ws, fcos, fsin, widx, qnw, knw);
  attn_mfma<<<dim3(512), 256, 0, stream>>>(q_ws, k_ws, vt_ws, att_o);
  to_bf16_plain<<<(E_ * HD_ / 8 + 255) / 256, 256, 0, stream>>>(wo, wo_bf, E_ * HD_);
  if (big)
    gemm_8ph<0, 256><<<dim3(E_ / 256, (B_ * S_) / 256), 512, 0, stream>>>(
        att_o, wo_bf, HD_, HD_ / 64, nullptr, nullptr, nullptr, out, E_, 0);
  else
    gemm_8ph<0, 128><<<dim3(E_ / 128, (B_ * S_) / 256), 512, 0, stream>>>(
        att_o, wo_bf, HD_, HD_ / 64, nullptr, nullptr, nullptr, out, E_, 0);
  (void)in_sizes; (void)n_in; (void)out_size;
}